// Round 16
// baseline (290.602 us; speedup 1.0000x reference)
//
#include <hip/hip_runtime.h>
#include <math.h>

typedef _Float16 f16;
typedef _Float16 f16x2 __attribute__((ext_vector_type(2)));
typedef _Float16 f16x4 __attribute__((ext_vector_type(4)));
typedef _Float16 f16x8 __attribute__((ext_vector_type(8)));
typedef float f32x4 __attribute__((ext_vector_type(4)));
typedef float f32x16 __attribute__((ext_vector_type(16)));

// ---------------------------------------------------------------------------
// Ligand repack: (96, V, K) fp32 -> wp[t][ch][VP] f16 (round-2 layout).
// ---------------------------------------------------------------------------
template<int V, int K, int VP>
__global__ void repack_kernel(const float* __restrict__ w, f16* __restrict__ wp) {
    int i = blockIdx.x * 256 + threadIdx.x;
    if (i >= K * 96 * VP) return;
    int v = i % VP, ch = (i / VP) % 96, t = i / (VP * 96);
    float val = (v < V) ? w[(ch * V + v) * K + t] : 0.f;
    wp[i] = (f16)val;
}

// ---------------------------------------------------------------------------
// Protein repack: CONFLICT-FREE B layout (r14, proven).
// ---------------------------------------------------------------------------
__global__ void repack_pro_kernel(const float* __restrict__ w, f16* __restrict__ wp) {
    constexpr int V = 25, K = 8;
    int i = blockIdx.x * 256 + threadIdx.x;     // [0, 8*6*64*8)
    if (i >= K * 6 * 64 * 8) return;
    int e = i & 7, l = (i >> 3) & 63, c6 = (i >> 9) % 6, t = i / (512 * 6);
    int r16 = l & 15, g = l >> 4;
    int ch = c6 * 16 + r16, v = g * 8 + e;
    float val = (v < V) ? w[(ch * V + v) * K + t] : 0.f;
    wp[i] = (f16)val;
}

// ---------------------------------------------------------------------------
// PROTEIN. T14-lite pipelined version of the proven r14/r15 kernel:
//  * CH=128 chunks, DOUBLE-buffered (2x10.9KB + 49.2KB weights = 72.4KB,
//    2 blocks/CU). Per chunk: issue loads(c+1) [4 float4s, STATIC NAMES,
//    16 regs -- r3/r5/r9 spilled holding 48-192] -> compute(c) hides the
//    ~900cy HBM latency under 96 MFMAs -> write(c+1) -> ONE barrier.
//  * sched_barrier(0) after load-issue pins the prefetch point.
//  * prologue hides chunk-0 latency under the weight->LDS copy.
//  * staging/swizzle/B-layout byte-identical to r14 (proven correct).
// ---------------------------------------------------------------------------
__global__ __launch_bounds__(256, 2) void conv_pro_kernel(
    const float* __restrict__ in,    // (B, 25, 1000) f32
    const f16*   __restrict__ wp,    // conflict-free layout, 49152 B
    const float* __restrict__ bias,  // (96)
    float* __restrict__ feat,        // (B, 192)
    int feat_off)
{
    constexpr int V = 25, L = 1000, KT = 8, LOUT = 993;
    constexpr int CH  = 128;          // output rows per chunk
    constexpr int NC  = 8;            // chunks (8*128 = 1024 >= 993+7)
    constexpr int BR  = 136;          // buffer rows (128 + 7 halo, pad 136)
    constexpr int RSB = 80;           // row stride bytes
    constexpr int P4  = BR / 4;       // 34 p-quads
    constexpr int NVP = 13;           // vocab pairs
    constexpr int NU  = NVP * P4;     // 442 staging units
    constexpr int NW  = KT * 6 * 64 * 8;  // 24576 f16 (49152 B)

    __shared__ __align__(16) char s_buf[2][BR * RSB];  // 21.76 KB
    __shared__ __align__(16) f16  s_w[NW];             // 49.15 KB
    __shared__ float s_red[4 * 96];                    // 1.5 KB

    const int tid  = threadIdx.x;
    const int wave = tid >> 6;        // 0..3
    const int lane = tid & 63;
    const int g    = lane >> 4;       // k-oct (0..3)
    const int r16  = lane & 15;       // A-row / B-col within 16-tile
    const size_t b = blockIdx.x;
    const float* gs = in + b * (size_t)(V * L);

    // ---- register staging slots: STATIC names, 16 regs total ----
    float4 xa0, xa1, xb0, xb1;

    auto issue_loads = [&](int c) {
        const float4 z4 = {0.f, 0.f, 0.f, 0.f};
        {   // unit a: i = tid < 442 always; v2 <= 7 so both rows valid
            const int v2 = tid / P4, p4 = tid - v2 * P4;
            const int gp = c * CH + 4 * p4;
            xa0 = z4; xa1 = z4;
            if (gp < L) {
                xa0 = *(const float4*)(gs + (size_t)(2 * v2) * L + gp);
                xa1 = *(const float4*)(gs + (size_t)(2 * v2 + 1) * L + gp);
            }
        }
        {   // unit b: i = 256+tid, valid while < 442
            const int i = 256 + tid;
            xb0 = z4; xb1 = z4;
            if (i < NU) {
                const int v2 = i / P4, p4 = i - v2 * P4;
                const int gp = c * CH + 4 * p4;
                if (gp < L) {
                    xb0 = *(const float4*)(gs + (size_t)(2 * v2) * L + gp);
                    if (2 * v2 + 1 < V)
                        xb1 = *(const float4*)(gs + (size_t)(2 * v2 + 1) * L + gp);
                }
            }
        }
    };

    auto write_rs = [&](char* sb) {
        {   const int v2 = tid / P4, p4 = tid - v2 * P4;
            const int p = 4 * p4, pb = 4 * v2;
            const int slot = pb & 48, sub = pb & 12;
            const float va[4] = {xa0.x, xa0.y, xa0.z, xa0.w};
            const float vb[4] = {xa1.x, xa1.y, xa1.z, xa1.w};
            #pragma unroll
            for (int j = 0; j < 4; ++j) {
                const int row = p + j;
                const int swz = ((row >> 3) & 3) << 4;
                f16x2 hv = { (f16)va[j], (f16)vb[j] };
                *(f16x2*)(sb + row * RSB + ((slot ^ swz) + sub)) = hv;
            }
        }
        {   const int i = 256 + tid;
            if (i < NU) {
                const int v2 = i / P4, p4 = i - v2 * P4;
                const int p = 4 * p4, pb = 4 * v2;
                const int slot = pb & 48, sub = pb & 12;
                const float va[4] = {xb0.x, xb0.y, xb0.z, xb0.w};
                const float vb[4] = {xb1.x, xb1.y, xb1.z, xb1.w};
                #pragma unroll
                for (int j = 0; j < 4; ++j) {
                    const int row = p + j;
                    const int swz = ((row >> 3) & 3) << 4;
                    f16x2 hv = { (f16)va[j], (f16)vb[j] };
                    *(f16x2*)(sb + row * RSB + ((slot ^ swz) + sub)) = hv;
                }
            }
        }
    };

    // ---- prologue: issue chunk-0 loads; weight copy + pad-zero fill the
    //      latency window; barrier separates pad writes from staging writes.
    issue_loads(0);
    {
        const f16x8* wg = (const f16x8*)wp;
        f16x8* wl = (f16x8*)s_w;
        #pragma unroll
        for (int u = 0; u < NW / 8 / 256; ++u)       // 12 iters
            wl[u * 256 + tid] = wg[u * 256 + tid];
    }
    for (int i = tid; i < 2 * BR; i += 256) {        // zero v-pad slot both bufs
        const int bsel = i / BR, row = i - bsel * BR;
        const int swz = ((row >> 3) & 3) << 4;
        *(f16x8*)(&s_buf[bsel][0] + row * RSB + (48 ^ swz)) = (f16x8){};
    }
    __syncthreads();                  // pads ordered before staging overwrites
    write_rs(&s_buf[0][0]);
    __syncthreads();                  // chunk 0 staged

    float runmax[6];
    #pragma unroll
    for (int c6 = 0; c6 < 6; ++c6) runmax[c6] = -3.0e38f;

    for (int c = 0; c < NC; ++c) {
        if (c + 1 < NC) issue_loads(c + 1);          // prefetch next chunk
        __builtin_amdgcn_sched_barrier(0);           // pin issue point

        // ---- compute chunk c: wave owns rows [wave*32, wave*32+31] ----
        const char* sb = &s_buf[c & 1][0];
        f32x4 acc[2][6] = {};
        #pragma unroll 1
        for (int t = 0; t < KT; ++t) {
            f16x8 bf[6];
            #pragma unroll
            for (int c6 = 0; c6 < 6; ++c6)
                bf[c6] = *(const f16x8*)(s_w + ((t * 6 + c6) * 64 + lane) * 8);
            #pragma unroll
            for (int rt = 0; rt < 2; ++rt) {
                const int row = wave * 32 + rt * 16 + r16 + t;   // <= 134 < 136
                const int swz = ((row >> 3) & 3) << 4;
                f16x8 a = *(const f16x8*)(sb + row * RSB + ((g * 16) ^ swz));
                #pragma unroll
                for (int c6 = 0; c6 < 6; ++c6)
                    acc[rt][c6] = __builtin_amdgcn_mfma_f32_16x16x32_f16(a, bf[c6], acc[rt][c6], 0, 0, 0);
            }
        }
        // ---- fold acc into runmax; C/D: col=lane&15, row=g*4+i ----
        #pragma unroll
        for (int rt = 0; rt < 2; ++rt) {
            const int pt = c * CH + wave * 32 + rt * 16;
            if (pt + 16 <= LOUT) {
                #pragma unroll
                for (int c6 = 0; c6 < 6; ++c6)
                    #pragma unroll
                    for (int i = 0; i < 4; ++i)
                        runmax[c6] = fmaxf(runmax[c6], acc[rt][c6][i]);
            } else {
                const int p0g = pt + g * 4;
                #pragma unroll
                for (int c6 = 0; c6 < 6; ++c6)
                    #pragma unroll
                    for (int i = 0; i < 4; ++i)
                        if (p0g + i < LOUT) runmax[c6] = fmaxf(runmax[c6], acc[rt][c6][i]);
            }
        }

        if (c + 1 < NC) write_rs(&s_buf[(c + 1) & 1][0]);  // land prefetch
        __syncthreads();              // one barrier per chunk
    }

    // ---- reduce: channel c6*16+r16 held by g-groups {r16, +16, +32, +48} ----
    #pragma unroll
    for (int c6 = 0; c6 < 6; ++c6) {
        runmax[c6] = fmaxf(runmax[c6], __shfl_xor(runmax[c6], 16, 64));
        runmax[c6] = fmaxf(runmax[c6], __shfl_xor(runmax[c6], 32, 64));
    }
    if (lane < 16) {
        #pragma unroll
        for (int c6 = 0; c6 < 6; ++c6)
            s_red[wave * 96 + c6 * 16 + lane] = runmax[c6];
    }
    __syncthreads();
    if (tid < 96) {
        float m = fmaxf(fmaxf(s_red[tid], s_red[96 + tid]),
                        fmaxf(s_red[192 + tid], s_red[288 + tid]));
        feat[b * 192 + feat_off + tid] = fmaxf(m + bias[tid], 0.f);
    }
}

// ---------------------------------------------------------------------------
// LIGAND branch: round-2 kernel (proven; ~25 us).
// ---------------------------------------------------------------------------
__global__ __launch_bounds__(384) void conv_lig_kernel(
    const float* __restrict__ in,    // (B, 64, 100) f32
    const f16*   __restrict__ wp,    // (4, 96, 64) f16
    const float* __restrict__ bias,  // (96)
    float* __restrict__ feat,        // (B, 192)
    int feat_off)
{
    constexpr int V = 64, L = 100, KT = 4, VP = 64, KSTEPS = 4;
    constexpr int LP = 132, RS = 72, NTILES = 4, LOUT = 97;
    constexpr int RSB = RS * 2, NQ = V / 4;
    __shared__ __align__(16) char s_raw[LP * RSB];

    const int tid  = threadIdx.x;
    const int b    = blockIdx.x;
    const int wave = tid >> 6;
    const int lane = tid & 63;
    const int colw = wave % 3;
    const int roww = wave / 3;
    const int q    = lane >> 5;
    const int r    = lane & 31;

    {   // zero LDS (covers row pad)
        float4 z = {0.f, 0.f, 0.f, 0.f};
        float4* sz = (float4*)s_raw;
        for (int i = tid; i < LP * RSB / 16; i += 384) sz[i] = z;
    }
    __syncthreads();

    const float* gin = in + (size_t)b * (V * L);
    for (int i = tid; i < NQ * L; i += 384) {
        int q4 = i / L, p = i - q4 * L;
        const float* gp = gin + q4 * 4 * L + p;
        f16x4 hv = { (f16)gp[0], (f16)gp[L], (f16)gp[2 * L], (f16)gp[3 * L] };
        int off = (8 * q4) ^ (((p >> 3) & 3) << 4);
        *(f16x4*)(s_raw + p * RSB + off) = hv;
    }

    f16x8 bfr[KT][KSTEPS];
    #pragma unroll
    for (int t = 0; t < KT; ++t)
        #pragma unroll
        for (int ks = 0; ks < KSTEPS; ++ks)
            bfr[t][ks] = *(const f16x8*)(wp + (t * 96 + colw * 32 + r) * VP + ks * 16 + q * 8);

    __syncthreads();

    float runmax = -3.0e38f;
    for (int it = 0; it < NTILES / 2; ++it) {
        const int p0 = (roww * (NTILES / 2) + it) * 32;
        f32x16 acc = {};
        #pragma unroll
        for (int t = 0; t < KT; ++t) {
            int row = p0 + r + t;
            if (row > LP - 1) row = LP - 1;          // clamped row is zero
            const char* ap = s_raw + row * RSB;
            const int swz = ((row >> 3) & 3) << 4;
            #pragma unroll
            for (int ks = 0; ks < KSTEPS; ++ks) {
                f16x8 af = *(const f16x8*)(ap + ((ks * 32 + q * 16) ^ swz));
                acc = __builtin_amdgcn_mfma_f32_32x32x16_f16(af, bfr[t][ks], acc, 0, 0, 0);
            }
        }
        #pragma unroll
        for (int i = 0; i < 16; ++i) {
            int rr = (i & 3) + 8 * (i >> 2) + 4 * q;
            if (p0 + rr < LOUT) runmax = fmaxf(runmax, acc[i]);
        }
    }
    runmax = fmaxf(runmax, __shfl_xor(runmax, 32, 64));

    __syncthreads();
    float* s_red = (float*)s_raw;     // [2][96]
    if (lane < 32) s_red[roww * 96 + colw * 32 + r] = runmax;
    __syncthreads();
    if (tid < 96) {
        float m = fmaxf(s_red[tid], s_red[96 + tid]);
        feat[(size_t)b * 192 + feat_off + tid] = fmaxf(m + bias[tid], 0.f);
    }
}

// ---------------------------------------------------------------------------
// Gram + L2 normalize + readout (4 samples/block, one wave each).
// ---------------------------------------------------------------------------
__global__ __launch_bounds__(256) void gram_affinity_kernel(
    const float* __restrict__ feat, const float* __restrict__ w_aff,
    const float* __restrict__ b_aff, float* __restrict__ out, int B)
{
    const int lane = threadIdx.x & 63;
    const int wid  = threadIdx.x >> 6;
    const int b    = blockIdx.x * 4 + wid;

    __shared__ float s_x[4][192];

    if (b < B) {
        const float* fp = feat + (size_t)b * 192;
        for (int i = lane; i < 192; i += 64) s_x[wid][i] = fp[i];
    }
    __syncthreads();

    if (b < B) {
        float ssum = 0.f, sdot = 0.f;
        #pragma unroll
        for (int t = 0; t < 16; ++t) {
            const int jk = t * 64 + lane;
            const int j = jk >> 5, k = jk & 31;
            float gg = 0.f;
            #pragma unroll
            for (int i = 0; i < 6; ++i)
                gg = fmaf(s_x[wid][i * 32 + j], s_x[wid][i * 32 + k], gg);
            ssum = fmaf(gg, gg, ssum);
            sdot = fmaf(gg, w_aff[jk], sdot);
        }
        #pragma unroll
        for (int off = 32; off >= 1; off >>= 1) {
            ssum += __shfl_xor(ssum, off, 64);
            sdot += __shfl_xor(sdot, off, 64);
        }
        if (lane == 0) out[b] = sdot / (sqrtf(ssum) + 1e-12f) + b_aff[0];
    }
}

extern "C" void kernel_launch(void* const* d_in, const int* in_sizes, int n_in,
                              void* d_out, int out_size, void* d_ws, size_t ws_size,
                              hipStream_t stream)
{
    const float* protein = (const float*)d_in[0];  // (B, 25, 1000)
    const float* ligand  = (const float*)d_in[1];  // (B, 64, 100)
    const float* w_pro   = (const float*)d_in[2];  // (96, 25, 8)
    const float* b_pro   = (const float*)d_in[3];  // (96,)
    const float* w_lig   = (const float*)d_in[4];  // (96, 64, 4)
    const float* b_lig   = (const float*)d_in[5];  // (96,)
    const float* w_aff   = (const float*)d_in[6];  // (1024,)
    const float* b_aff   = (const float*)d_in[7];  // (1,)
    float* out = (float*)d_out;
    const int B = out_size;                        // 4096

    float* feat   = (float*)d_ws;                              // (B,192) f32
    f16*   wpackP = (f16*)((char*)d_ws + (size_t)B * 192 * 4); // 24576 f16
    f16*   wpackL = wpackP + 24576;                            // 4*96*64 f16

    repack_pro_kernel<<<96, 256, 0, stream>>>(w_pro, wpackP);
    repack_kernel<64, 4, 64><<<96, 256, 0, stream>>>(w_lig, wpackL);

    // ligand branch -> feat[:, 0:96]
    conv_lig_kernel<<<B, 384, 0, stream>>>(ligand, wpackL, b_lig, feat, 0);
    // protein branch -> feat[:, 96:192]
    conv_pro_kernel<<<B, 256, 0, stream>>>(protein, wpackP, b_pro, feat, 96);

    gram_affinity_kernel<<<(B + 3) / 4, 256, 0, stream>>>(feat, w_aff, b_aff, out, B);
}

// Round 17
// 249.427 us; speedup vs baseline: 1.1651x; 1.1651x over previous
//
#include <hip/hip_runtime.h>
#include <math.h>

typedef _Float16 f16;
typedef _Float16 f16x2 __attribute__((ext_vector_type(2)));
typedef _Float16 f16x8 __attribute__((ext_vector_type(8)));
typedef float f32x4 __attribute__((ext_vector_type(4)));

// ---------------------------------------------------------------------------
// Protein repack: CONFLICT-FREE B layout (r14, proven).
//   idx = ((t*6+c6)*64 + lane)*8 + e; ch = c6*16 + (lane&15); v = (lane>>4)*8+e.
// ---------------------------------------------------------------------------
__global__ void repack_pro_kernel(const float* __restrict__ w, f16* __restrict__ wp) {
    constexpr int V = 25, K = 8;
    int i = blockIdx.x * 256 + threadIdx.x;     // [0, 8*6*64*8)
    if (i >= K * 6 * 64 * 8) return;
    int e = i & 7, l = (i >> 3) & 63, c6 = (i >> 9) % 6, t = i / (512 * 6);
    int r16 = l & 15, g = l >> 4;
    int ch = c6 * 16 + r16, v = g * 8 + e;
    float val = (v < V) ? w[(ch * V + v) * K + t] : 0.f;
    wp[i] = (f16)val;
}

// ---------------------------------------------------------------------------
// Ligand repack: same conflict-free style, tk = t*2+ks (KS=2, V=64 no pad).
//   idx = ((tk*6+c6)*64 + lane)*8 + e; ch = c6*16+r16; v = ks*32 + g*8 + e.
// ---------------------------------------------------------------------------
__global__ void repack_lig_kernel(const float* __restrict__ w, f16* __restrict__ wp) {
    constexpr int V = 64, K = 4;
    int i = blockIdx.x * 256 + threadIdx.x;     // [0, 8*6*64*8)
    if (i >= 8 * 6 * 64 * 8) return;
    int e = i & 7, l = (i >> 3) & 63, c6 = (i >> 9) % 6, tk = i / (512 * 6);
    int t = tk >> 1, ks = tk & 1;
    int r16 = l & 15, g = l >> 4;
    int ch = c6 * 16 + r16, v = ks * 32 + g * 8 + e;
    wp[i] = (f16)w[(ch * V + v) * K + t];
}

// ---------------------------------------------------------------------------
// MERGED conv kernel, 8192 blocks x 512 thr, launch_bounds(512,4), 73.3KB LDS
// (2 blocks/CU). bid < B: protein path (r15 VERBATIM -- best measured).
// bid >= B: ligand path in the same 16x16x32 style (V=64, no pad, 7 tiles
// over waves 0..6, acc=24 regs). Ligand blocks backfill CUs around protein
// blocks -> ligand wall-time hides under protein.
// ---------------------------------------------------------------------------
__global__ __launch_bounds__(512, 4) void conv_kernel(
    const float* __restrict__ pro,   // (B, 25, 1000) f32
    const f16*   __restrict__ wpP,   // protein weights, conflict-free
    const float* __restrict__ bP,    // (96)
    const float* __restrict__ lig,   // (B, 64, 100) f32
    const f16*   __restrict__ wpL,   // ligand weights, conflict-free
    const float* __restrict__ bL,    // (96)
    float* __restrict__ feat,        // (B, 192)
    int B)
{
    __shared__ __align__(16) char s_raw[264 * 80];   // 21.1 KB (lig: 120*144)
    __shared__ __align__(16) f16  s_w[24576];        // 49.15 KB (both paths)
    __shared__ float s_red[8 * 96];                  // 3 KB

    const int tid  = threadIdx.x;
    const int wave = tid >> 6;        // 0..7
    const int lane = tid & 63;
    const int g    = lane >> 4;       // k-oct
    const int r16  = lane & 15;       // A-row / B-col in 16-tile

    if ((int)blockIdx.x < B) {
        // ================= PROTEIN path (r15 verbatim) =================
        constexpr int V = 25, L = 1000, KT = 8, LOUT = 993;
        constexpr int CH = 256, NC = 4, BR = 264, RSB = 80;
        constexpr int P4 = BR / 4, NVP = 13, NU = NVP * P4;   // 858
        const size_t b = blockIdx.x;
        const float* gs = pro + b * (size_t)(V * L);

        {   const f16x8* wg = (const f16x8*)wpP;
            f16x8* wl = (f16x8*)s_w;
            #pragma unroll
            for (int u = 0; u < 24576 / 8 / 512; ++u)    // 6 iters
                wl[u * 512 + tid] = wg[u * 512 + tid];
        }
        for (int row = tid; row < BR; row += 512) {      // zero v-pad slot
            const int swz = ((row >> 3) & 3) << 4;
            *(f16x8*)(s_raw + row * RSB + (48 ^ swz)) = (f16x8){};
        }
        __syncthreads();

        float runmax[6];
        #pragma unroll
        for (int c6 = 0; c6 < 6; ++c6) runmax[c6] = -3.0e38f;

        for (int c = 0; c < NC; ++c) {
            if (c) __syncthreads();
            #pragma unroll
            for (int u = 0; u < 2; ++u) {
                const int i = u * 512 + tid;
                if (i < NU) {
                    const int v2 = i / P4, p4 = i - v2 * P4;
                    const int p  = 4 * p4;
                    const int gp = c * CH + p;
                    float4 x0 = {0.f, 0.f, 0.f, 0.f}, x1 = {0.f, 0.f, 0.f, 0.f};
                    if (gp < L) {
                        x0 = *(const float4*)(gs + (size_t)(2 * v2) * L + gp);
                        if (2 * v2 + 1 < V)
                            x1 = *(const float4*)(gs + (size_t)(2 * v2 + 1) * L + gp);
                    }
                    const int pb = 4 * v2;
                    const int slot = pb & 48, sub = pb & 12;
                    const float vx0[4] = {x0.x, x0.y, x0.z, x0.w};
                    const float vx1[4] = {x1.x, x1.y, x1.z, x1.w};
                    #pragma unroll
                    for (int j = 0; j < 4; ++j) {
                        const int row = p + j;
                        const int swz = ((row >> 3) & 3) << 4;
                        f16x2 hv = { (f16)vx0[j], (f16)vx1[j] };
                        *(f16x2*)(s_raw + row * RSB + ((slot ^ swz) + sub)) = hv;
                    }
                }
            }
            __syncthreads();

            f32x4 acc[2][6] = {};
            #pragma unroll 1
            for (int t = 0; t < KT; ++t) {
                f16x8 bf[6];
                #pragma unroll
                for (int c6 = 0; c6 < 6; ++c6)
                    bf[c6] = *(const f16x8*)(s_w + ((t * 6 + c6) * 64 + lane) * 8);
                #pragma unroll
                for (int rt = 0; rt < 2; ++rt) {
                    const int row = wave * 32 + rt * 16 + r16 + t;
                    const int swz = ((row >> 3) & 3) << 4;
                    f16x8 a = *(const f16x8*)(s_raw + row * RSB + ((g * 16) ^ swz));
                    #pragma unroll
                    for (int c6 = 0; c6 < 6; ++c6)
                        acc[rt][c6] = __builtin_amdgcn_mfma_f32_16x16x32_f16(a, bf[c6], acc[rt][c6], 0, 0, 0);
                }
            }
            #pragma unroll
            for (int rt = 0; rt < 2; ++rt) {
                const int pt = c * CH + wave * 32 + rt * 16;
                if (pt + 16 <= LOUT) {
                    #pragma unroll
                    for (int c6 = 0; c6 < 6; ++c6)
                        #pragma unroll
                        for (int i = 0; i < 4; ++i)
                            runmax[c6] = fmaxf(runmax[c6], acc[rt][c6][i]);
                } else {
                    const int p0g = pt + g * 4;
                    #pragma unroll
                    for (int c6 = 0; c6 < 6; ++c6)
                        #pragma unroll
                        for (int i = 0; i < 4; ++i)
                            if (p0g + i < LOUT) runmax[c6] = fmaxf(runmax[c6], acc[rt][c6][i]);
                }
            }
        }

        #pragma unroll
        for (int c6 = 0; c6 < 6; ++c6) {
            runmax[c6] = fmaxf(runmax[c6], __shfl_xor(runmax[c6], 16, 64));
            runmax[c6] = fmaxf(runmax[c6], __shfl_xor(runmax[c6], 32, 64));
        }
        if (lane < 16) {
            #pragma unroll
            for (int c6 = 0; c6 < 6; ++c6)
                s_red[wave * 96 + c6 * 16 + lane] = runmax[c6];
        }
        __syncthreads();
        if (tid < 96) {
            float m = s_red[tid];
            #pragma unroll
            for (int w = 1; w < 8; ++w) m = fmaxf(m, s_red[w * 96 + tid]);
            feat[b * 192 + 96 + tid] = fmaxf(m + bP[tid], 0.f);
        }
    } else {
        // ================= LIGAND path (16x16x32, V=64 no pad) =================
        constexpr int V = 64, L = 100, KT = 4, LOUT = 97;
        constexpr int BR = 120, RSB = 144;      // 120 rows x 144B = 17.3 KB
        constexpr int P4 = BR / 4, NVP = 32, NU = NVP * P4;   // 960
        const size_t b = blockIdx.x - B;
        const float* gs = lig + b * (size_t)(V * L);

        {   const f16x8* wg = (const f16x8*)wpL;
            f16x8* wl = (f16x8*)s_w;
            #pragma unroll
            for (int u = 0; u < 24576 / 8 / 512; ++u)    // 6 iters
                wl[u * 512 + tid] = wg[u * 512 + tid];
        }
        // stage whole sample transposed (rows >= L zero-filled)
        #pragma unroll
        for (int u = 0; u < 2; ++u) {
            const int i = u * 512 + tid;
            if (i < NU) {
                const int v2 = i / P4, p4 = i - v2 * P4;
                const int p  = 4 * p4;
                float4 x0 = {0.f, 0.f, 0.f, 0.f}, x1 = {0.f, 0.f, 0.f, 0.f};
                if (p < L) {
                    x0 = *(const float4*)(gs + (size_t)(2 * v2) * L + p);
                    x1 = *(const float4*)(gs + (size_t)(2 * v2 + 1) * L + p);
                }
                const int pb = 4 * v2;                    // 0..124
                const int slot = pb & 0x70, sub = pb & 12;
                const float vx0[4] = {x0.x, x0.y, x0.z, x0.w};
                const float vx1[4] = {x1.x, x1.y, x1.z, x1.w};
                #pragma unroll
                for (int j = 0; j < 4; ++j) {
                    const int row = p + j;
                    const int swz = ((row >> 3) & 3) << 4;
                    f16x2 hv = { (f16)vx0[j], (f16)vx1[j] };
                    *(f16x2*)(s_raw + row * RSB + ((slot ^ swz) + sub)) = hv;
                }
            }
        }
        __syncthreads();

        // compute: wave w < 7 owns row-tile w (rows w*16..w*16+15), all 96 ch
        if (wave < 7) {
            f32x4 acc[6] = {};
            #pragma unroll 1
            for (int t = 0; t < KT; ++t) {
                #pragma unroll
                for (int ks = 0; ks < 2; ++ks) {
                    f16x8 bf[6];
                    #pragma unroll
                    for (int c6 = 0; c6 < 6; ++c6)
                        bf[c6] = *(const f16x8*)(s_w + (((t * 2 + ks) * 6 + c6) * 64 + lane) * 8);
                    const int row = wave * 16 + r16 + t;          // <= 114 < 120
                    const int swz = ((row >> 3) & 3) << 4;
                    f16x8 a = *(const f16x8*)(s_raw + row * RSB + ((ks * 64 + g * 16) ^ swz));
                    #pragma unroll
                    for (int c6 = 0; c6 < 6; ++c6)
                        acc[c6] = __builtin_amdgcn_mfma_f32_16x16x32_f16(a, bf[c6], acc[c6], 0, 0, 0);
                }
            }
            float runmax[6];
            const int p0g = wave * 16 + g * 4;    // C/D: col=lane&15, row=g*4+i
            #pragma unroll
            for (int c6 = 0; c6 < 6; ++c6) {
                runmax[c6] = -3.0e38f;
                #pragma unroll
                for (int i = 0; i < 4; ++i)
                    if (p0g + i < LOUT) runmax[c6] = fmaxf(runmax[c6], acc[c6][i]);
                runmax[c6] = fmaxf(runmax[c6], __shfl_xor(runmax[c6], 16, 64));
                runmax[c6] = fmaxf(runmax[c6], __shfl_xor(runmax[c6], 32, 64));
            }
            if (lane < 16) {
                #pragma unroll
                for (int c6 = 0; c6 < 6; ++c6)
                    s_red[wave * 96 + c6 * 16 + lane] = runmax[c6];
            }
        }
        __syncthreads();
        if (tid < 96) {
            float m = s_red[tid];
            #pragma unroll
            for (int w = 1; w < 7; ++w) m = fmaxf(m, s_red[w * 96 + tid]);
            feat[b * 192 + tid] = fmaxf(m + bL[tid], 0.f);
        }
    }
}

// ---------------------------------------------------------------------------
// Gram + L2 normalize + readout (4 samples/block, one wave each).
// ---------------------------------------------------------------------------
__global__ __launch_bounds__(256) void gram_affinity_kernel(
    const float* __restrict__ feat, const float* __restrict__ w_aff,
    const float* __restrict__ b_aff, float* __restrict__ out, int B)
{
    const int lane = threadIdx.x & 63;
    const int wid  = threadIdx.x >> 6;
    const int b    = blockIdx.x * 4 + wid;

    __shared__ float s_x[4][192];

    if (b < B) {
        const float* fp = feat + (size_t)b * 192;
        for (int i = lane; i < 192; i += 64) s_x[wid][i] = fp[i];
    }
    __syncthreads();

    if (b < B) {
        float ssum = 0.f, sdot = 0.f;
        #pragma unroll
        for (int t = 0; t < 16; ++t) {
            const int jk = t * 64 + lane;
            const int j = jk >> 5, k = jk & 31;
            float gg = 0.f;
            #pragma unroll
            for (int i = 0; i < 6; ++i)
                gg = fmaf(s_x[wid][i * 32 + j], s_x[wid][i * 32 + k], gg);
            ssum = fmaf(gg, gg, ssum);
            sdot = fmaf(gg, w_aff[jk], sdot);
        }
        #pragma unroll
        for (int off = 32; off >= 1; off >>= 1) {
            ssum += __shfl_xor(ssum, off, 64);
            sdot += __shfl_xor(sdot, off, 64);
        }
        if (lane == 0) out[b] = sdot / (sqrtf(ssum) + 1e-12f) + b_aff[0];
    }
}

extern "C" void kernel_launch(void* const* d_in, const int* in_sizes, int n_in,
                              void* d_out, int out_size, void* d_ws, size_t ws_size,
                              hipStream_t stream)
{
    const float* protein = (const float*)d_in[0];  // (B, 25, 1000)
    const float* ligand  = (const float*)d_in[1];  // (B, 64, 100)
    const float* w_pro   = (const float*)d_in[2];  // (96, 25, 8)
    const float* b_pro   = (const float*)d_in[3];  // (96,)
    const float* w_lig   = (const float*)d_in[4];  // (96, 64, 4)
    const float* b_lig   = (const float*)d_in[5];  // (96,)
    const float* w_aff   = (const float*)d_in[6];  // (1024,)
    const float* b_aff   = (const float*)d_in[7];  // (1,)
    float* out = (float*)d_out;
    const int B = out_size;                        // 4096

    float* feat   = (float*)d_ws;                              // (B,192) f32
    f16*   wpackP = (f16*)((char*)d_ws + (size_t)B * 192 * 4); // 24576 f16
    f16*   wpackL = wpackP + 24576;                            // 24576 f16

    repack_pro_kernel<<<96, 256, 0, stream>>>(w_pro, wpackP);
    repack_lig_kernel<<<96, 256, 0, stream>>>(w_lig, wpackL);

    // merged conv: blocks [0,B) protein -> feat[:,96:], [B,2B) ligand -> feat[:,:96]
    conv_kernel<<<2 * B, 512, 0, stream>>>(
        protein, wpackP, b_pro, ligand, wpackL, b_lig, feat, B);

    gram_affinity_kernel<<<(B + 3) / 4, 256, 0, stream>>>(feat, w_aff, b_aff, out, B);
}